// Round 3
// baseline (271.891 us; speedup 1.0000x reference)
//
#include <hip/hip_runtime.h>

// SphericalBessel: Miller downward recurrence, fp64 internal, fp32 out.
// N=65536, K=32, L=32, lstart = 32 + int(sqrt(320)) = 49.
// out[n, l, k] = y[l] * (sin(x)/x) / y[0] * sqrt(2/pi) * k,  x = r[n]*k.
//
// v3b: one thread computes FOUR adjacent k-chains (k = 4q+1..4q+4).
//  - dwordx4 nontemporal stores via ext_vector_type(4) float (the builtin
//    rejects HIP's struct float4): wave writes 1024B per store instruction
//    in 8x128B segments (fill-like), 4x fewer store instructions than v2.
//  - ILP-4: four independent fp64 recurrence chains interleave, hiding
//    dependent-FMA latency inside a single wave.
//  - Two-pass structure retained (pass 1: carries only -> y0; pass 2:
//    recompute + scale + store) to avoid a y[32] array (no scratch).
// fp64 trajectory identical to v2 (passed, absmax 4.0 well under the
// 2%-of-absmax threshold); sinf perturbs only the normalization (~3e-5 rel).

#define K_MAX 32
#define L_MAX 32
#define LSTART 49  // L_MAX + int(sqrt(10*L_MAX))

typedef float floatx4 __attribute__((ext_vector_type(4)));

__global__ __launch_bounds__(256) void sph_bessel_kernel(
    const float* __restrict__ r, float* __restrict__ out, int n_total) {
    const int tid = blockIdx.x * blockDim.x + threadIdx.x;
    if (tid >= n_total * (K_MAX / 4)) return;

    const int n = tid >> 3;   // radius index
    const int q = tid & 7;    // k-quad: k = 4q+1 .. 4q+4
    const double rd = (double)r[n];

    double inv[4], scale[4], j1[4], j2[4];

#pragma unroll
    for (int c = 0; c < 4; ++c) {
        const double kd = (double)(4 * q + c + 1);
        inv[c] = 1.0 / (rd * kd);   // reference divides each step; 1 ulp diff
        j1[c]  = 1.0;               // is benign vs the threshold
        j2[c]  = 0.0;
    }

    // ---- Pass 1: full downward recurrence, carries only -> y0 per chain ----
#pragma unroll
    for (int i = LSTART; i >= 1; --i) {
        const double c2i = 2.0 * (double)i + 1.0;
#pragma unroll
        for (int c = 0; c < 4; ++c) {
            const double j0 = fma(c2i * inv[c], j1[c], -j2[c]);
            j2[c] = j1[c];
            j1[c] = j0;
        }
    }

    // Normalization: true j_0(x) = sin(x)/x (fp32 sin: ~3e-5 relative on the
    // scalar normalization only — validated passing in v2).
#pragma unroll
    for (int c = 0; c < 4; ++c) {
        const double kd = (double)(4 * q + c + 1);
        const double x  = rd * kd;
        const double true_j0 = (double)sinf((float)x) * inv[c];
        scale[c] = (true_j0 / j1[c]) * 0.79788456080286535588 * kd;
        j1[c] = 1.0;
        j2[c] = 0.0;
    }

    // ---- Pass 2: identical chains, scale + pack + dwordx4 store ----
    float* op = out + (size_t)n * (L_MAX * K_MAX) + 4 * q;
#pragma unroll
    for (int i = LSTART; i >= 1; --i) {
        const double c2i = 2.0 * (double)i + 1.0;
        double j0c[4];
#pragma unroll
        for (int c = 0; c < 4; ++c) {
            const double j0 = fma(c2i * inv[c], j1[c], -j2[c]);
            j2[c] = j1[c];
            j1[c] = j0;
            j0c[c] = j0;
        }
        if (i <= L_MAX) {
            floatx4 v;
            v.x = (float)(j0c[0] * scale[0]);
            v.y = (float)(j0c[1] * scale[1]);
            v.z = (float)(j0c[2] * scale[2]);
            v.w = (float)(j0c[3] * scale[3]);
            __builtin_nontemporal_store(
                v, (floatx4*)(op + (size_t)(i - 1) * K_MAX));
        }
    }
}

extern "C" void kernel_launch(void* const* d_in, const int* in_sizes, int n_in,
                              void* d_out, int out_size, void* d_ws, size_t ws_size,
                              hipStream_t stream) {
    const float* r = (const float*)d_in[0];
    float* out = (float*)d_out;
    const int n_total = in_sizes[0];  // 65536

    const int total_threads = n_total * (K_MAX / 4);  // 4 k-chains per thread
    const int block = 256;
    const int grid = (total_threads + block - 1) / block;
    sph_bessel_kernel<<<grid, block, 0, stream>>>(r, out, n_total);
}

// Round 4
// 255.137 us; speedup vs baseline: 1.0657x; 1.0657x over previous
//
#include <hip/hip_runtime.h>

// SphericalBessel: Miller downward recurrence, fp64 internal, fp32 out.
// N=65536, K=32, L=32, lstart = 32 + int(sqrt(320)) = 49.
// out[n, l, k] = y[l] * (sin(x)/x) / y[0] * sqrt(2/pi) * k,  x = r[n]*k.
//
// v4 = revert to v1 (best measured: 254.26 µs).
// Session findings (R0-R3): dur_us = harness poison-fill (~161-176 µs,
// 77-84% HBM peak, fixed) + kernel (~93 µs). Kernel time is INVARIANT
// across 2x fp64-work, 2x occupancy, 4x ILP, 4x store-width changes ->
// memory-system floor: 256 MiB streamed writes + eviction of the fill's
// dirty poison lines ~= 512 MiB HBM traffic ~= 85 µs at 6.3 TB/s.
// Nontemporal stores REGRESS (+16 µs, v3b): they put HBM latency on the
// critical path instead of retiring into the LLC (output == 256 MiB ==
// LLC size). Keep regular scalar stores.

#define K_MAX 32
#define L_MAX 32
#define LSTART 49  // L_MAX + int(sqrt(10*L_MAX))

__global__ __launch_bounds__(256) void sph_bessel_kernel(
    const float* __restrict__ r, float* __restrict__ out, int n_total) {
    const int tid = blockIdx.x * blockDim.x + threadIdx.x;
    if (tid >= n_total * K_MAX) return;

    const int n  = tid >> 5;   // radius index
    const int kq = tid & 31;   // k index, k = kq+1
    const double kd = (double)(kq + 1);

    const double x   = (double)r[n] * kd;
    const double inv = 1.0 / x;   // reference divides each step; 1 ulp diff is
                                  // benign vs the 2%-of-absmax threshold

    double j1 = 1.0, j2 = 0.0;
    double y[L_MAX];

    // Steps i = 49 .. 33: run the recurrence, discard.
#pragma unroll
    for (int i = LSTART; i > L_MAX; --i) {
        const double j0 = fma((2.0 * i + 1.0) * inv, j1, -j2);
        j2 = j1;
        j1 = j0;
    }
    // Steps i = 32 .. 1: y[i-1] = j0.
#pragma unroll
    for (int i = L_MAX; i >= 1; --i) {
        const double j0 = fma((2.0 * i + 1.0) * inv, j1, -j2);
        j2 = j1;
        j1 = j0;
        y[i - 1] = j0;
    }

    // true j_0(x) = sin(x)/x ; normalize Miller solution and apply sqrt(2/pi)*k.
    const double true_j0 = sin(x) * inv;
    const double scale   = (true_j0 / y[0]) * 0.79788456080286535588 * kd;

    float* op = out + (size_t)n * (L_MAX * K_MAX) + kq;
#pragma unroll
    for (int l = 0; l < L_MAX; ++l) {
        op[(size_t)l * K_MAX] = (float)(y[l] * scale);
    }
}

extern "C" void kernel_launch(void* const* d_in, const int* in_sizes, int n_in,
                              void* d_out, int out_size, void* d_ws, size_t ws_size,
                              hipStream_t stream) {
    const float* r = (const float*)d_in[0];
    float* out = (float*)d_out;
    const int n_total = in_sizes[0];  // 65536

    const int total_threads = n_total * K_MAX;
    const int block = 256;
    const int grid = (total_threads + block - 1) / block;
    sph_bessel_kernel<<<grid, block, 0, stream>>>(r, out, n_total);
}